// Round 9
// baseline (961.167 us; speedup 1.0000x reference)
//
#include <hip/hip_runtime.h>
#include <hip/hip_bf16.h>
#include <math.h>

#define GN 19            // graph nodes
#define BB 256
#define TT 256

typedef short short8 __attribute__((ext_vector_type(8)));
typedef float f4 __attribute__((ext_vector_type(4)));

union Frag { int i[4]; short8 s; };

// wave-local LDS ordering fence: wait LDS ops, NO vmcnt drain, no barrier.
#define LWAIT() __asm__ volatile("s_waitcnt lgkmcnt(0)" ::: "memory")
// workgroup barrier WITHOUT vmcnt(0) drain: global loads/stores stay in flight.
#define WGBAR() __asm__ volatile("s_waitcnt lgkmcnt(0)\ns_barrier" ::: "memory")

// packed RNE float pair -> bf16 pair (v_cvt_pk_bf16_f32 on gfx950)
__device__ __forceinline__ int pkbf(float a, float b) {
    __hip_bfloat162 h2 = __float22bfloat162_rn(make_float2(a, b));
    union { __hip_bfloat162 h; int i; } u; u.h = h2; return u.i;
}

__device__ __forceinline__ float rl(float v, int j) {
    return __int_as_float(__builtin_amdgcn_readlane(__float_as_int(v), j));
}
__device__ __forceinline__ float fexp2(float x) { return __builtin_amdgcn_exp2f(x); }
__device__ __forceinline__ float frcp(float x)  { return __builtin_amdgcn_rcpf(x); }
__device__ __forceinline__ float sigm(float x)  { return frcp(1.f + fexp2(-1.4426950408889634f * x)); }
__device__ __forceinline__ float tanha(float x) { float e = fexp2(2.8853900817779268f * x); return 1.f - 2.f * frcp(e + 1.f); }

// ---------------------------------------------------------------------------
// Kernel A: graph encoder via bf16 MFMA (16x16x32).  (unchanged from R4)
// ---------------------------------------------------------------------------
__global__ __launch_bounds__(64) void encoder_mfma(
    const float* __restrict__ conn,   // (G,19,19)
    const int*   __restrict__ mask,   // (G)
    const float* __restrict__ w1_w,   // (64,19)
    const float* __restrict__ w1_b,   // (64)
    const float* __restrict__ w2_w,   // (64,64)
    const float* __restrict__ w2_b,   // (64)
    float* __restrict__ emb,          // (G,64)
    int num_graphs)
{
    __shared__ float S[2304];         // 9216 B, reused 4 ways
    __shared__ float dis[32];
    __shared__ float ps[256];

    const int t = threadIdx.x;
    const int l15 = t & 15;
    const int quad = t >> 4;

    float km[8];
    #pragma unroll
    for (int j = 0; j < 8; ++j) km[j] = (quad * 8 + j < GN) ? 1.f : 0.f;

    int rr[6], cc[6];
    #pragma unroll
    for (int i = 0; i < 6; ++i) {
        int e = t + 64 * i;
        rr[i] = e / GN;
        cc[i] = e - rr[i] * GN;
    }

    Frag w1F[4];
    #pragma unroll
    for (int nt = 0; nt < 4; ++nt) {
        int n = nt * 16 + l15;
        #pragma unroll
        for (int p = 0; p < 4; ++p) {
            int k0 = quad * 8 + 2 * p, k1 = k0 + 1;
            float a = (k0 < GN) ? w1_w[n * GN + k0] : 0.f;
            float b = (k1 < GN) ? w1_w[n * GN + k1] : 0.f;
            w1F[nt].i[p] = pkbf(a, b);
        }
    }
    Frag w2F[2][4];
    #pragma unroll
    for (int kt = 0; kt < 2; ++kt)
        #pragma unroll
        for (int nt = 0; nt < 4; ++nt) {
            int n = nt * 16 + l15;
            #pragma unroll
            for (int p = 0; p < 4; ++p) {
                int k = kt * 32 + quad * 8 + 2 * p;
                w2F[kt][nt].i[p] = pkbf(w2_w[n * 64 + k], w2_w[n * 64 + k + 1]);
            }
        }
    float b1v[4], b2v[4];
    #pragma unroll
    for (int nt = 0; nt < 4; ++nt) {
        b1v[nt] = w1_b[nt * 16 + l15];
        b2v[nt] = w2_b[nt * 16 + l15];
    }

    float pf[6];
    {
        int g0 = blockIdx.x < num_graphs ? blockIdx.x : 0;
        const float* Ag = conn + (size_t)g0 * (GN * GN);
        #pragma unroll
        for (int i = 0; i < 6; ++i) {
            int e = t + 64 * i;
            if (e < GN * GN) pf[i] = Ag[e];
        }
    }

    #pragma unroll 1
    for (int g = blockIdx.x; g < num_graphs; g += gridDim.x) {
        #pragma unroll
        for (int i = 0; i < 4; ++i) {
            int s = t + 64 * i;
            int row = s >> 3, c4 = s & 7;
            f4 z = {0.f, 0.f, 0.f, 0.f};
            *(f4*)&S[row * 68 + c4 * 4] = z;
        }
        LWAIT();
        #pragma unroll
        for (int i = 0; i < 6; ++i) {
            if (t + 64 * i < GN * GN) S[rr[i] * 68 + cc[i]] = pf[i];
        }
        {
            int gn = g + gridDim.x;
            const float* Ag = conn + (size_t)(gn < num_graphs ? gn : g) * (GN * GN);
            #pragma unroll
            for (int i = 0; i < 6; ++i) {
                int e = t + 64 * i;
                if (e < GN * GN) pf[i] = Ag[e];
            }
        }
        LWAIT();

        if (t < 32) {
            float dv = 0.f;
            if (t < GN) {
                float d = 1.0f;
                #pragma unroll
                for (int c4 = 0; c4 < 8; ++c4) {
                    f4 v = *(f4*)&S[t * 68 + c4 * 4];
                    d += v.x + v.y + v.z + v.w;
                }
                dv = rsqrtf(d);
            }
            dis[t] = dv;
        }
        LWAIT();

        float dk[8];
        {
            f4 v0 = *(f4*)&dis[quad * 8];
            f4 v1 = *(f4*)&dis[quad * 8 + 4];
            dk[0]=v0.x; dk[1]=v0.y; dk[2]=v0.z; dk[3]=v0.w;
            dk[4]=v1.x; dk[5]=v1.y; dk[6]=v1.z; dk[7]=v1.w;
        }
        Frag aF[2], anF[2];
        #pragma unroll
        for (int mt = 0; mt < 2; ++mt) {
            int m = l15 + 16 * mt;
            float dm = dis[m];
            f4 v0 = *(f4*)&S[m * 68 + quad * 8];
            f4 v1 = *(f4*)&S[m * 68 + quad * 8 + 4];
            float av[8] = {v0.x, v0.y, v0.z, v0.w, v1.x, v1.y, v1.z, v1.w};
            float an[8];
            #pragma unroll
            for (int j = 0; j < 8; ++j) {
                int k = quad * 8 + j;
                an[j] = (av[j] + (m == k ? 1.f : 0.f)) * dm * dk[j];
            }
            #pragma unroll
            for (int p = 0; p < 4; ++p) {
                aF[mt].i[p]  = pkbf(av[2*p], av[2*p+1]);
                anF[mt].i[p] = pkbf(an[2*p], an[2*p+1]);
            }
        }
        LWAIT();

        #pragma unroll
        for (int mt = 0; mt < 2; ++mt)
            #pragma unroll
            for (int nt = 0; nt < 4; ++nt) {
                float bb = b1v[nt];
                f4 c = {bb, bb, bb, bb};
                c = __builtin_amdgcn_mfma_f32_16x16x32_bf16(aF[mt].s, w1F[nt].s, c, 0, 0, 0);
                int col = nt * 16 + l15;
                #pragma unroll
                for (int r = 0; r < 4; ++r)
                    S[col * 36 + (mt * 16 + quad * 4 + r)] = c[r];
            }
        LWAIT();

        Frag hF[4];
        #pragma unroll
        for (int nt = 0; nt < 4; ++nt) {
            int n = nt * 16 + l15;
            f4 v0 = *(f4*)&S[n * 36 + quad * 8];
            f4 v1 = *(f4*)&S[n * 36 + quad * 8 + 4];
            float vv[8] = {v0.x, v0.y, v0.z, v0.w, v1.x, v1.y, v1.z, v1.w};
            #pragma unroll
            for (int p = 0; p < 4; ++p)
                hF[nt].i[p] = pkbf(vv[2*p] * km[2*p], vv[2*p+1] * km[2*p+1]);
        }
        LWAIT();

        #pragma unroll
        for (int mt = 0; mt < 2; ++mt)
            #pragma unroll
            for (int nt = 0; nt < 4; ++nt) {
                f4 c = {0.f, 0.f, 0.f, 0.f};
                c = __builtin_amdgcn_mfma_f32_16x16x32_bf16(anF[mt].s, hF[nt].s, c, 0, 0, 0);
                int col = nt * 16 + l15;
                #pragma unroll
                for (int r = 0; r < 4; ++r)
                    S[(mt * 16 + quad * 4 + r) * 68 + col] = fmaxf(c[r], 0.f);
            }
        LWAIT();

        Frag xF[2][2];
        #pragma unroll
        for (int mt = 0; mt < 2; ++mt) {
            int m = l15 + 16 * mt;
            #pragma unroll
            for (int kt = 0; kt < 2; ++kt) {
                f4 v0 = *(f4*)&S[m * 68 + kt * 32 + quad * 8];
                f4 v1 = *(f4*)&S[m * 68 + kt * 32 + quad * 8 + 4];
                xF[mt][kt].i[0] = pkbf(v0.x, v0.y);
                xF[mt][kt].i[1] = pkbf(v0.z, v0.w);
                xF[mt][kt].i[2] = pkbf(v1.x, v1.y);
                xF[mt][kt].i[3] = pkbf(v1.z, v1.w);
            }
        }
        LWAIT();

        #pragma unroll
        for (int mt = 0; mt < 2; ++mt)
            #pragma unroll
            for (int nt = 0; nt < 4; ++nt) {
                float bb = b2v[nt];
                f4 c = {bb, bb, bb, bb};
                c = __builtin_amdgcn_mfma_f32_16x16x32_bf16(xF[mt][0].s, w2F[0][nt].s, c, 0, 0, 0);
                c = __builtin_amdgcn_mfma_f32_16x16x32_bf16(xF[mt][1].s, w2F[1][nt].s, c, 0, 0, 0);
                int col = nt * 16 + l15;
                #pragma unroll
                for (int r = 0; r < 4; ++r)
                    S[col * 36 + (mt * 16 + quad * 4 + r)] = c[r];
            }
        LWAIT();

        #pragma unroll
        for (int nt = 0; nt < 4; ++nt) {
            int n = nt * 16 + l15;
            f4 v0 = *(f4*)&S[n * 36 + quad * 8];
            f4 v1 = *(f4*)&S[n * 36 + quad * 8 + 4];
            float vv[8] = {v0.x, v0.y, v0.z, v0.w, v1.x, v1.y, v1.z, v1.w};
            #pragma unroll
            for (int p = 0; p < 4; ++p)
                hF[nt].i[p] = pkbf(vv[2*p] * km[2*p], vv[2*p+1] * km[2*p+1]);
        }

        float cs[4];
        #pragma unroll
        for (int nt = 0; nt < 4; ++nt) cs[nt] = 0.f;
        #pragma unroll
        for (int mt = 0; mt < 2; ++mt)
            #pragma unroll
            for (int nt = 0; nt < 4; ++nt) {
                f4 c = {0.f, 0.f, 0.f, 0.f};
                c = __builtin_amdgcn_mfma_f32_16x16x32_bf16(anF[mt].s, hF[nt].s, c, 0, 0, 0);
                if (mt == 0) {
                    cs[nt] += fmaxf(c[0], 0.f) + fmaxf(c[1], 0.f)
                            + fmaxf(c[2], 0.f) + fmaxf(c[3], 0.f);
                } else if (quad == 0) {
                    cs[nt] += fmaxf(c[0], 0.f) + fmaxf(c[1], 0.f) + fmaxf(c[2], 0.f);
                }
            }
        #pragma unroll
        for (int nt = 0; nt < 4; ++nt)
            ps[quad * 64 + nt * 16 + l15] = cs[nt];
        LWAIT();
        float tot = ps[t] + ps[64 + t] + ps[128 + t] + ps[192 + t];
        float mf = (float)mask[g];
        emb[(size_t)g * 64 + t] = tot * (1.f / 19.f) * mf;
        LWAIT();
    }
}

// ---------------------------------------------------------------------------
// Kernel X: xg = xin @ Wih^T  (fp32 vector, EXACT same dot ordering as the
// in-loop version -> bitwise-identical gates).  Thread = gate row (256),
// block processes 32 consecutive timestep-rows; x rows read via wave-uniform
// scalar loads (all lanes same address).
// ---------------------------------------------------------------------------
__global__ __launch_bounds__(256, 4) void xg_gemm(
    const float* __restrict__ xin,   // (BT, 64)
    const float* __restrict__ Wih,   // (256, 64)
    float* __restrict__ xg)          // (BT, 256)
{
    const int tid = threadIdx.x;
    float wi[64];
    {
        const float4* p = (const float4*)(Wih + tid * 64);
        #pragma unroll
        for (int j = 0; j < 16; ++j) ((float4*)wi)[j] = p[j];
    }
    const int row0 = blockIdx.x * 32;

    #pragma unroll 2
    for (int rr = 0; rr < 32; ++rr) {
        const float* __restrict__ xr = xin + (size_t)(row0 + rr) * 64;
        float n0 = 0.f, n1 = 0.f, n2 = 0.f, n3 = 0.f;
        #pragma unroll
        for (int j = 0; j < 64; j += 4) {
            n0 = fmaf(xr[j],     wi[j],     n0);
            n1 = fmaf(xr[j + 1], wi[j + 1], n1);
            n2 = fmaf(xr[j + 2], wi[j + 2], n2);
            n3 = fmaf(xr[j + 3], wi[j + 3], n3);
        }
        xg[(size_t)(row0 + rr) * 256 + tid] = (n0 + n1) + (n2 + n3);
    }
}

// ---------------------------------------------------------------------------
// Kernel B: LSTM layer 0 recurrence (xg-fed).  Thread tid owns gate row tid;
// only wh[64] in regs (VGPR ~80, no spill).  Per step: 1 coalesced dword
// load (2-step prefetch window >> HBM latency), 64 readlane-FMAs, 1 no-drain
// barrier, 4 gate ds_reads, activations.
// ---------------------------------------------------------------------------
__global__ __launch_bounds__(256, 1) void lstm_rec0(
    const float* __restrict__ xg,     // (B*T, 256)
    const float* __restrict__ Whh,
    const float* __restrict__ bih, const float* __restrict__ bhh,
    float* __restrict__ hseq)         // (B*T, 64)
{
    __shared__ float gs[2][256];
    const int tid = threadIdx.x;
    const int w = tid >> 6, l = tid & 63;
    const int b = blockIdx.x;

    float wh[64];
    {
        const float4* q = (const float4*)(Whh + tid * 64);
        #pragma unroll
        for (int j = 0; j < 16; ++j) ((float4*)wh)[j] = q[j];
    }
    const float bias = bih[tid] + bhh[tid];
    const float* __restrict__ xgb = xg + (size_t)b * TT * 256 + tid;

    float xc  = xgb[0];
    float xn1 = xgb[256];
    float h = 0.f, c = 0.f;

    #pragma unroll 1
    for (int t = 0; t < TT; ++t) {
        float xn2 = xgb[(size_t)(t + 2 < TT ? t + 2 : TT - 1) * 256];

        float a0 = bias + xc, a1 = 0.f, a2 = 0.f, a3 = 0.f;
        #pragma unroll
        for (int j = 0; j < 64; j += 4) {
            a0 = fmaf(rl(h, j),     wh[j],     a0);
            a1 = fmaf(rl(h, j + 1), wh[j + 1], a1);
            a2 = fmaf(rl(h, j + 2), wh[j + 2], a2);
            a3 = fmaf(rl(h, j + 3), wh[j + 3], a3);
        }
        gs[t & 1][tid] = (a0 + a1) + (a2 + a3);
        WGBAR();

        const float* gp = gs[t & 1];
        float gi = gp[l], gf = gp[64 + l], gg = gp[128 + l], go = gp[192 + l];
        c = sigm(gf) * c + sigm(gi) * tanha(gg);
        h = sigm(go) * tanha(c);
        if (w == 0) hseq[((size_t)b * TT + t) * 64 + l] = h;
        xc = xn1; xn1 = xn2;
    }
}

// ---------------------------------------------------------------------------
// Kernel C: LSTM layer 1 recurrence + FC head (xg-fed).
// ---------------------------------------------------------------------------
__global__ __launch_bounds__(256, 1) void lstm_rec1_head(
    const float* __restrict__ xg,     // (B*T, 256)
    const int*   __restrict__ mask,   // (B, T)
    const float* __restrict__ Whh,
    const float* __restrict__ bih, const float* __restrict__ bhh,
    const float* __restrict__ fc1_w, const float* __restrict__ fc1_b,
    const float* __restrict__ fc2_w, const float* __restrict__ fc2_b,
    float* __restrict__ out)          // (B, 2)
{
    __shared__ float gs[2][256];
    __shared__ int li_s;
    const int tid = threadIdx.x;
    const int w = tid >> 6, l = tid & 63;
    const int b = blockIdx.x;

    float wh[64];
    {
        const float4* q = (const float4*)(Whh + tid * 64);
        #pragma unroll
        for (int j = 0; j < 16; ++j) ((float4*)wh)[j] = q[j];
    }
    const float bias = bih[tid] + bhh[tid];

    gs[0][tid] = (float)mask[b * TT + tid];
    __syncthreads();
    if (tid == 0) {
        float sm = 0.f;
        for (int t = 0; t < TT; ++t) sm += gs[0][t];
        int li = (int)sm - 1;
        li = li < 0 ? 0 : (li > TT - 1 ? TT - 1 : li);
        li_s = li;
    }
    __syncthreads();
    const int lastidx = li_s;

    const float* __restrict__ xgb = xg + (size_t)b * TT * 256 + tid;
    float xc  = xgb[0];
    float xn1 = xgb[256];
    float h = 0.f, c = 0.f, hl = 0.f;

    #pragma unroll 1
    for (int t = 0; t < TT; ++t) {
        float xn2 = xgb[(size_t)(t + 2 < TT ? t + 2 : TT - 1) * 256];

        float a0 = bias + xc, a1 = 0.f, a2 = 0.f, a3 = 0.f;
        #pragma unroll
        for (int j = 0; j < 64; j += 4) {
            a0 = fmaf(rl(h, j),     wh[j],     a0);
            a1 = fmaf(rl(h, j + 1), wh[j + 1], a1);
            a2 = fmaf(rl(h, j + 2), wh[j + 2], a2);
            a3 = fmaf(rl(h, j + 3), wh[j + 3], a3);
        }
        gs[t & 1][tid] = (a0 + a1) + (a2 + a3);
        WGBAR();

        const float* gp = gs[t & 1];
        float gi = gp[l], gf = gp[64 + l], gg = gp[128 + l], go = gp[192 + l];
        c = sigm(gf) * c + sigm(gi) * tanha(gg);
        h = sigm(go) * tanha(c);
        if (t == lastidx) hl = h;
        xc = xn1; xn1 = xn2;
    }

    __syncthreads();
    if (w == 0 && l < 32) {
        float acc = fc1_b[l];
        const float* fw = fc1_w + l * 64;
        #pragma unroll
        for (int j = 0; j < 64; ++j)
            acc = fmaf(fw[j], rl(hl, j), acc);
        gs[0][l] = fmaxf(acc, 0.f);
    }
    __syncthreads();
    if (w == 0 && l < 2) {
        float acc = fc2_b[l];
        #pragma unroll
        for (int j = 0; j < 32; ++j)
            acc = fmaf(fc2_w[l * 32 + j], gs[0][j], acc);
        out[b * 2 + l] = acc;
    }
}

// ---------------------------------------------------------------------------
// Fallback kernels (R4-proven): used only if ws_size is too small for xg.
// ---------------------------------------------------------------------------
__global__ __launch_bounds__(256, 1) void lstm_l0_fb(
    const float* __restrict__ x,
    const float* __restrict__ Wih, const float* __restrict__ Whh,
    const float* __restrict__ bih, const float* __restrict__ bhh,
    float* __restrict__ hseq)
{
    __shared__ float gs[2][256];
    const int tid = threadIdx.x;
    const int w = tid >> 6, l = tid & 63;
    const int b = blockIdx.x;

    float wi[64], wh[64];
    {
        const float4* p = (const float4*)(Wih + tid * 64);
        const float4* q = (const float4*)(Whh + tid * 64);
        #pragma unroll
        for (int j = 0; j < 16; ++j) {
            ((float4*)wi)[j] = p[j];
            ((float4*)wh)[j] = q[j];
        }
    }
    const float bias = bih[tid] + bhh[tid];
    const float* __restrict__ xb = x + (size_t)b * TT * 64;

    float xc;
    {
        float n0 = 0.f, n1 = 0.f, n2 = 0.f, n3 = 0.f;
        #pragma unroll
        for (int j = 0; j < 64; j += 4) {
            n0 = fmaf(xb[j],     wi[j],     n0);
            n1 = fmaf(xb[j + 1], wi[j + 1], n1);
            n2 = fmaf(xb[j + 2], wi[j + 2], n2);
            n3 = fmaf(xb[j + 3], wi[j + 3], n3);
        }
        xc = (n0 + n1) + (n2 + n3);
    }

    float h = 0.f, c = 0.f;

    #pragma unroll 1
    for (int t = 0; t < TT; ++t) {
        const f4* __restrict__ ern = (const f4*)(xb + (t + 1 < TT ? t + 1 : TT - 1) * 64);
        f4 xr[16];
        #pragma unroll
        for (int k = 0; k < 16; ++k) xr[k] = ern[k];

        float a0 = bias + xc, a1 = 0.f, a2 = 0.f, a3 = 0.f;
        #pragma unroll
        for (int j = 0; j < 64; j += 4) {
            a0 = fmaf(rl(h, j),     wh[j],     a0);
            a1 = fmaf(rl(h, j + 1), wh[j + 1], a1);
            a2 = fmaf(rl(h, j + 2), wh[j + 2], a2);
            a3 = fmaf(rl(h, j + 3), wh[j + 3], a3);
        }
        gs[t & 1][tid] = (a0 + a1) + (a2 + a3);
        WGBAR();
        const float* gp = gs[t & 1];
        float gi = gp[l], gf = gp[64 + l], gg = gp[128 + l], go = gp[192 + l];
        c = sigm(gf) * c + sigm(gi) * tanha(gg);
        h = sigm(go) * tanha(c);
        if (w == 0) hseq[((size_t)b * TT + t) * 64 + l] = h;

        float n0 = 0.f, n1 = 0.f, n2 = 0.f, n3 = 0.f;
        #pragma unroll
        for (int k = 0; k < 16; ++k) {
            f4 v = xr[k];
            n0 = fmaf(v.x, wi[4*k],     n0);
            n1 = fmaf(v.y, wi[4*k + 1], n1);
            n2 = fmaf(v.z, wi[4*k + 2], n2);
            n3 = fmaf(v.w, wi[4*k + 3], n3);
        }
        xc = (n0 + n1) + (n2 + n3);
    }
}

__global__ __launch_bounds__(256, 1) void lstm_l1_head_fb(
    const float* __restrict__ x,
    const int*   __restrict__ mask,
    const float* __restrict__ Wih, const float* __restrict__ Whh,
    const float* __restrict__ bih, const float* __restrict__ bhh,
    const float* __restrict__ fc1_w, const float* __restrict__ fc1_b,
    const float* __restrict__ fc2_w, const float* __restrict__ fc2_b,
    float* __restrict__ out)
{
    __shared__ float gs[2][256];
    __shared__ int li_s;
    const int tid = threadIdx.x;
    const int w = tid >> 6, l = tid & 63;
    const int b = blockIdx.x;

    float wi[64], wh[64];
    {
        const float4* p = (const float4*)(Wih + tid * 64);
        const float4* q = (const float4*)(Whh + tid * 64);
        #pragma unroll
        for (int j = 0; j < 16; ++j) {
            ((float4*)wi)[j] = p[j];
            ((float4*)wh)[j] = q[j];
        }
    }
    const float bias = bih[tid] + bhh[tid];

    gs[0][tid] = (float)mask[b * TT + tid];
    __syncthreads();
    if (tid == 0) {
        float s = 0.f;
        for (int t = 0; t < TT; ++t) s += gs[0][t];
        int li = (int)s - 1;
        li = li < 0 ? 0 : (li > TT - 1 ? TT - 1 : li);
        li_s = li;
    }
    __syncthreads();
    const int lastidx = li_s;

    const float* __restrict__ xb = x + (size_t)b * TT * 64;

    float xc;
    {
        float n0 = 0.f, n1 = 0.f, n2 = 0.f, n3 = 0.f;
        #pragma unroll
        for (int j = 0; j < 64; j += 4) {
            n0 = fmaf(xb[j],     wi[j],     n0);
            n1 = fmaf(xb[j + 1], wi[j + 1], n1);
            n2 = fmaf(xb[j + 2], wi[j + 2], n2);
            n3 = fmaf(xb[j + 3], wi[j + 3], n3);
        }
        xc = (n0 + n1) + (n2 + n3);
    }

    float h = 0.f, c = 0.f, hl = 0.f;

    #pragma unroll 1
    for (int t = 0; t < TT; ++t) {
        const f4* __restrict__ ern = (const f4*)(xb + (t + 1 < TT ? t + 1 : TT - 1) * 64);
        f4 xr[16];
        #pragma unroll
        for (int k = 0; k < 16; ++k) xr[k] = ern[k];

        float a0 = bias + xc, a1 = 0.f, a2 = 0.f, a3 = 0.f;
        #pragma unroll
        for (int j = 0; j < 64; j += 4) {
            a0 = fmaf(rl(h, j),     wh[j],     a0);
            a1 = fmaf(rl(h, j + 1), wh[j + 1], a1);
            a2 = fmaf(rl(h, j + 2), wh[j + 2], a2);
            a3 = fmaf(rl(h, j + 3), wh[j + 3], a3);
        }
        gs[t & 1][tid] = (a0 + a1) + (a2 + a3);
        WGBAR();
        const float* gp = gs[t & 1];
        float gi = gp[l], gf = gp[64 + l], gg = gp[128 + l], go = gp[192 + l];
        c = sigm(gf) * c + sigm(gi) * tanha(gg);
        h = sigm(go) * tanha(c);
        if (t == lastidx) hl = h;

        float n0 = 0.f, n1 = 0.f, n2 = 0.f, n3 = 0.f;
        #pragma unroll
        for (int k = 0; k < 16; ++k) {
            f4 v = xr[k];
            n0 = fmaf(v.x, wi[4*k],     n0);
            n1 = fmaf(v.y, wi[4*k + 1], n1);
            n2 = fmaf(v.z, wi[4*k + 2], n2);
            n3 = fmaf(v.w, wi[4*k + 3], n3);
        }
        xc = (n0 + n1) + (n2 + n3);
    }

    __syncthreads();
    if (w == 0 && l < 32) {
        float acc = fc1_b[l];
        const float* fw = fc1_w + l * 64;
        #pragma unroll
        for (int j = 0; j < 64; ++j)
            acc = fmaf(fw[j], rl(hl, j), acc);
        gs[0][l] = fmaxf(acc, 0.f);
    }
    __syncthreads();
    if (w == 0 && l < 2) {
        float acc = fc2_b[l];
        #pragma unroll
        for (int j = 0; j < 32; ++j)
            acc = fmaf(fc2_w[l * 32 + j], gs[0][j], acc);
        out[b * 2 + l] = acc;
    }
}

// ---------------------------------------------------------------------------
extern "C" void kernel_launch(void* const* d_in, const int* in_sizes, int n_in,
                              void* d_out, int out_size, void* d_ws, size_t ws_size,
                              hipStream_t stream)
{
    const float* conn  = (const float*)d_in[0];
    const int*   mask  = (const int*)  d_in[1];
    const float* w1_w  = (const float*)d_in[2];
    const float* w1_b  = (const float*)d_in[3];
    const float* w2_w  = (const float*)d_in[4];
    const float* w2_b  = (const float*)d_in[5];
    const float* Wih0  = (const float*)d_in[6];
    const float* Whh0  = (const float*)d_in[7];
    const float* bih0  = (const float*)d_in[8];
    const float* bhh0  = (const float*)d_in[9];
    const float* Wih1  = (const float*)d_in[10];
    const float* Whh1  = (const float*)d_in[11];
    const float* bih1  = (const float*)d_in[12];
    const float* bhh1  = (const float*)d_in[13];
    const float* fc1_w = (const float*)d_in[14];
    const float* fc1_b = (const float*)d_in[15];
    const float* fc2_w = (const float*)d_in[16];
    const float* fc2_b = (const float*)d_in[17];

    float* out = (float*)d_out;
    const int num_graphs = BB * TT;   // 65536

    // ws layout (floats): emb [0,4.19M) | xg [4.19M,20.97M) | h0seq [20.97M,25.17M)
    const size_t embF = (size_t)BB * TT * 64;     //  4.19 M floats (16.8 MB)
    const size_t xgF  = (size_t)BB * TT * 256;    // 16.78 M floats (67.1 MB)
    const size_t needBytes = (embF * 2 + xgF) * sizeof(float);   // 100.7 MB

    float* emb = (float*)d_ws;

    encoder_mfma<<<8192, 64, 0, stream>>>(
        conn, mask, w1_w, w1_b, w2_w, w2_b, emb, num_graphs);

    if (ws_size >= needBytes) {
        float* xg    = emb + embF;
        float* h0seq = xg + xgF;

        xg_gemm<<<num_graphs / 32, 256, 0, stream>>>(emb, Wih0, xg);
        lstm_rec0<<<BB, 256, 0, stream>>>(xg, Whh0, bih0, bhh0, h0seq);
        xg_gemm<<<num_graphs / 32, 256, 0, stream>>>(h0seq, Wih1, xg);
        lstm_rec1_head<<<BB, 256, 0, stream>>>(
            xg, mask, Whh1, bih1, bhh1, fc1_w, fc1_b, fc2_w, fc2_b, out);
    } else {
        float* h0seq = emb + embF;
        lstm_l0_fb<<<BB, 256, 0, stream>>>(emb, Wih0, Whh0, bih0, bhh0, h0seq);
        lstm_l1_head_fb<<<BB, 256, 0, stream>>>(
            h0seq, mask, Wih1, Whh1, bih1, bhh1,
            fc1_w, fc1_b, fc2_w, fc2_b, out);
    }
}